// Round 6
// baseline (28.747 us; speedup 1.0000x reference)
//
#include <hip/hip_runtime.h>
#include <math.h>

#define BB 32
#define LL 128
#define DD 256
#define HH 1024            // 4*D
#define MAGIC 0x5F3C9A71u  // != 0xAAAAAAAA poison

__device__ __forceinline__ float waveReduceSum(float v) {
#pragma unroll
    for (int m = 32; m >= 1; m >>= 1) v += __shfl_xor(v, m, 64);
    return v;
}

// One dispatch, 256 blocks x 256 threads. Block (b=blk>>3, g=blk&7) owns
// a1 rows [g*16,g*16+16) and a2 rows [g*16,g*16+16) of batch b, cached in LDS.
// Cluster sync (8 blocks of a batch) via MAGIC-token flags in d_ws:
//  - release store after data write; acquire-load spin before data read.
//  - stale MAGIC from a previous graph replay is benign: the guarded data is
//    bit-identical across replays (deterministic recompute of same inputs).
__global__ __launch_bounds__(256) void fused_spin(
    const float* __restrict__ a1, const int* __restrict__ len1,
    const float* __restrict__ a2, const int* __restrict__ len2,
    const float* __restrict__ fcw, const float* __restrict__ fcb,
    const float* __restrict__ ww, float* __restrict__ out,
    float* __restrict__ wsS, float* __restrict__ wsPart,
    unsigned* __restrict__ sdone, unsigned* __restrict__ pdone)
{
    const int blk  = blockIdx.x;   // 0..255
    const int b    = blk >> 3;
    const int g    = blk & 7;
    const int tid  = threadIdx.x;
    const int wave = tid >> 6;
    const int lane = tid & 63;

    __shared__ __align__(16) float4 wws4[DD / 4];
    __shared__ __align__(16) float4 A1l4[16][DD / 4];   // 16 KB
    __shared__ __align__(16) float4 A2l4[16][DD / 4];   // 16 KB
    __shared__ float s1[LL], s2[LL], E1[LL], E2m[LL];
    __shared__ float redS[4], redM[4];
    __shared__ float rs_own[16], cs_own[16];
    __shared__ __align__(16) float ps[DD];

    if (tid < DD / 4) wws4[tid] = ((const float4*)ww)[tid];
    __syncthreads();

    // ---- phase 1: own 32 row-dots; rows cached in LDS; write s to ws ----
    {
        const int k = tid >> 4;        // local row 0..15
        const int t = tid & 15;
        const size_t rowoff = ((size_t)b * LL + g * 16 + k) * DD;
        const float4* __restrict__ r1 = (const float4*)(a1 + rowoff);
        const float4* __restrict__ r2 = (const float4*)(a2 + rowoff);
        float d1 = 0.f, d2 = 0.f;
#pragma unroll
        for (int q = 0; q < 4; ++q) {
            const int idx = t + 16 * q;
            const float4 w  = wws4[idx];
            const float4 v1 = r1[idx];
            A1l4[k][idx] = v1;
            d1 += v1.x * w.x + v1.y * w.y + v1.z * w.z + v1.w * w.w;
            const float4 v2 = r2[idx];
            A2l4[k][idx] = v2;
            d2 += v2.x * w.x + v2.y * w.y + v2.z * w.z + v2.w * w.w;
        }
#pragma unroll
        for (int m = 1; m <= 8; m <<= 1) {
            d1 += __shfl_xor(d1, m, 64);
            d2 += __shfl_xor(d2, m, 64);
        }
        if (t == 0) {
            wsS[b * LL + g * 16 + k]        = d1;
            wsS[4096 + b * LL + g * 16 + k] = d2;
        }
    }
    __syncthreads();
    if (tid == 0)
        __hip_atomic_store(&sdone[blk], MAGIC, __ATOMIC_RELEASE, __HIP_MEMORY_SCOPE_AGENT);
    if (tid < 8) {
        while (__hip_atomic_load(&sdone[b * 8 + tid], __ATOMIC_ACQUIRE,
                                 __HIP_MEMORY_SCOPE_AGENT) != MAGIC)
            __builtin_amdgcn_s_sleep(1);
    }
    __syncthreads();

    // ---- load full s for this batch ----
    if (tid < LL) s1[tid]      = wsS[b * LL + tid];
    else          s2[tid - LL] = wsS[4096 + b * LL + (tid - LL)];
    __syncthreads();

    const int l1 = len1[b];
    const int l2 = len2[b];

    // ---- stats: factorized softmax. rs[i]=e^{s1_i}*S2-m_i, cs[j]=e^{-s2_j}*S1-m'_j,
    //      denom=S1*S2-M  (masked pairs contribute exp(|d|<1e-7)~=1; exp(-1e7)=0) ----
    {
        float v = 0.f;
        if (tid < LL) {
            const float e = expf(s1[tid]);
            E1[tid] = e;
            if (tid < l1) v = e;
        } else {
            const int j = tid - LL;
            const float e = expf(-s2[j]);
            E2m[j] = e;
            if (j < l2) v = e;
        }
        v = waveReduceSum(v);
        if (lane == 0) redS[wave] = v;     // waves 0,1 -> S1; waves 2,3 -> S2
    }
    __syncthreads();
    // global masked-pair count M (valid pairs only)
    {
        int cnt = 0;
        const int base = tid * 64;
#pragma unroll 4
        for (int q = 0; q < 64; ++q) {
            const int n = base + q;
            const int i = n >> 7, j = n & 127;
            if (i < l1 && j < l2 && fabsf(s1[i] - s2[j]) < 1e-7f) cnt++;
        }
        float fc_ = waveReduceSum((float)cnt);
        if (lane == 0) redM[wave] = fc_;
    }
    __syncthreads();
    const float S1   = redS[0] + redS[1];
    const float S2   = redS[2] + redS[3];
    const float Mtot = redM[0] + redM[1] + redM[2] + redM[3];
    const float dinv = 1.0f / (S1 * S2 - Mtot);

    // own-row mask counts -> rs_own/cs_own (alpha weights pre-scaled by dinv)
    {
        const int k = tid >> 4, t = tid & 15;
        const int gi = g * 16 + k;
        int mi = 0, mj = 0;
        if (gi < l1) {
            const float si = s1[gi];
            for (int j = t; j < l2; j += 16)
                if (fabsf(si - s2[j]) < 1e-7f) mi++;
        }
        if (gi < l2) {
            const float sj = s2[gi];
            for (int i = t; i < l1; i += 16)
                if (fabsf(s1[i] - sj) < 1e-7f) mj++;
        }
#pragma unroll
        for (int m = 1; m <= 8; m <<= 1) {
            mi += __shfl_xor(mi, m, 64);
            mj += __shfl_xor(mj, m, 64);
        }
        if (t == 0) {
            rs_own[k] = (gi < l1) ? (E1[gi] * S2 - (float)mi) * dinv : 0.f;
            cs_own[k] = (gi < l2) ? (E2m[gi] * S1 - (float)mj) * dinv : 0.f;
        }
    }
    __syncthreads();

    // ---- pooled partial from LDS-cached rows ----
    {
        const float* __restrict__ A1s = (const float*)A1l4;
        const float* __restrict__ A2s = (const float*)A2l4;
        float p = 0.f;
#pragma unroll
        for (int k = 0; k < 16; ++k)
            p += rs_own[k] * A1s[k * DD + tid] - cs_own[k] * A2s[k * DD + tid];
        wsPart[(size_t)blk * DD + tid] = p;
    }
    __syncthreads();
    if (tid == 0)
        __hip_atomic_store(&pdone[blk], MAGIC, __ATOMIC_RELEASE, __HIP_MEMORY_SCOPE_AGENT);
    if (tid < 8) {
        while (__hip_atomic_load(&pdone[b * 8 + tid], __ATOMIC_ACQUIRE,
                                 __HIP_MEMORY_SCOPE_AGENT) != MAGIC)
            __builtin_amdgcn_s_sleep(1);
    }
    __syncthreads();

    // ---- sum the 8 partials (fixed order -> deterministic) ----
    {
        float p = 0.f;
#pragma unroll
        for (int g2 = 0; g2 < 8; ++g2)
            p += wsPart[(size_t)(b * 8 + g2) * DD + tid];
        ps[tid] = p;
    }
    __syncthreads();

    // ---- FC + tanh for own 128 h ----
    {
        const int h    = g * 128 + (tid >> 1);
        const int half = tid & 1;
        const float4* __restrict__ wrow =
            (const float4*)(fcw + (size_t)h * DD) + half * 32;
        const float4* __restrict__ pp = (const float4*)ps + half * 32;
        float ax = 0.f, ay = 0.f, az = 0.f, aw = 0.f;
#pragma unroll 8
        for (int q = 0; q < 32; ++q) {
            const float4 v = wrow[q];
            const float4 u = pp[q];
            ax += v.x * u.x; ay += v.y * u.y; az += v.z * u.z; aw += v.w * u.w;
        }
        float sres = (ax + ay) + (az + aw);
        sres += __shfl_xor(sres, 1, 64);
        if (half == 0) out[(size_t)b * HH + h] = tanhf(sres + fcb[h]);
    }
}

extern "C" void kernel_launch(void* const* d_in, const int* in_sizes, int n_in,
                              void* d_out, int out_size, void* d_ws, size_t ws_size,
                              hipStream_t stream) {
    const float* a1   = (const float*)d_in[0];
    const int*   len1 = (const int*)d_in[1];
    const float* a2   = (const float*)d_in[2];
    const int*   len2 = (const int*)d_in[3];
    const float* fcw  = (const float*)d_in[4];
    const float* fcb  = (const float*)d_in[5];
    const float* ww   = (const float*)d_in[6];
    float* out = (float*)d_out;

    float*    wsS    = (float*)d_ws;              // 8192 floats
    float*    wsPart = wsS + 8192;                // 65536 floats
    unsigned* sdone  = (unsigned*)(wsPart + 65536); // 256 words
    unsigned* pdone  = sdone + 256;               // 256 words

    fused_spin<<<256, 256, 0, stream>>>(a1, len1, a2, len2, fcw, fcb, ww, out,
                                        wsS, wsPart, sdone, pdone);
}

// Round 7
// 24.077 us; speedup vs baseline: 1.1939x; 1.1939x over previous
//
#include <hip/hip_runtime.h>
#include <math.h>

#define BB 32
#define LL 128
#define DD 256
#define HH 1024   // 4*D

__device__ __forceinline__ float waveReduceSum(float v) {
#pragma unroll
    for (int m = 32; m >= 1; m >>= 1) v += __shfl_xor(v, m, 64);
    return v;
}

// One dispatch, one block per batch, 1024 threads.
// Factorized softmax: exp(s1_i - s2_j) = e^{s1_i} * e^{-s2_j}; masked pairs
// (|we|<1e-7, incl. all invalid with we==0) contribute exp(-1e7)=0 after
// masking, and their unmasked value e^{we}~=1 (|we|<1e-7) is removed by count
// subtraction. denom = S1*S2 - M. No global max needed: |s| <~ 6 => no overflow.
__global__ __launch_bounds__(1024) void batch_all_kernel(
    const float* __restrict__ a1, const int* __restrict__ len1,
    const float* __restrict__ a2, const int* __restrict__ len2,
    const float* __restrict__ fcw, const float* __restrict__ fcb,
    const float* __restrict__ ww, float* __restrict__ out)
{
    const int b    = blockIdx.x;
    const int tid  = threadIdx.x;
    const int wave = tid >> 6;     // 0..15
    const int lane = tid & 63;

    __shared__ __align__(16) float4 wws4[DD / 4];
    __shared__ float s1[LL], s2[LL], E1[LL], E2m[LL];
    __shared__ float rsv[LL], csv[LL];
    __shared__ float part[1024];
    __shared__ float redS[16], redM[16];
    __shared__ __align__(16) float4 ps4[DD / 4];

    const int l1 = len1[b];
    const int l2 = len2[b];

    if (tid < DD / 4) wws4[tid] = ((const float4*)ww)[tid];
    __syncthreads();

    const float* __restrict__ A1 = a1 + (size_t)b * LL * DD;
    const float* __restrict__ A2 = a2 + (size_t)b * LL * DD;

    // ---- phase 1: 256 row-dots, 4 threads per row ----
    {
        const int r = tid >> 2;            // 0..255
        const int t = tid & 3;
        const float4* __restrict__ row = (const float4*)
            ((r < LL) ? (A1 + (size_t)r * DD) : (A2 + (size_t)(r - LL) * DD));
        float ax = 0.f, ay = 0.f, az = 0.f, aw = 0.f;
#pragma unroll
        for (int q = 0; q < 16; ++q) {
            const int idx = q * 4 + t;
            const float4 v = row[idx];
            const float4 w = wws4[idx];
            ax += v.x * w.x; ay += v.y * w.y; az += v.z * w.z; aw += v.w * w.w;
        }
        float s = (ax + ay) + (az + aw);
        s += __shfl_xor(s, 1, 64);
        s += __shfl_xor(s, 2, 64);
        if (t == 0) { if (r < LL) s1[r] = s; else s2[r - LL] = s; }
    }
    __syncthreads();

    // ---- phase 2: E1=e^{s1}, E2m=e^{-s2}; S1,S2 over valid; M = masked count ----
    {
        float v = 0.f;
        if (tid < LL) {
            const float e = expf(s1[tid]);
            E1[tid] = e;
            if (tid < l1) v = e;
        } else if (tid < 2 * LL) {
            const int j = tid - LL;
            const float e = expf(-s2[j]);
            E2m[j] = e;
            if (j < l2) v = e;
        }
        v = waveReduceSum(v);
        if (lane == 0) redS[wave] = v;     // waves 0,1 -> S1; waves 2,3 -> S2
    }
    __syncthreads();                       // s1/s2 fully visible for count loop
    {
        int cnt = 0;
        const int base = tid * 16;
#pragma unroll
        for (int q = 0; q < 16; ++q) {
            const int n = base + q;
            const int i = n >> 7, j = n & 127;
            if (i < l1 && j < l2 && fabsf(s1[i] - s2[j]) < 1e-7f) cnt++;
        }
        float fcnt = waveReduceSum((float)cnt);
        if (lane == 0) redM[wave] = fcnt;
    }
    __syncthreads();
    const float S1 = redS[0] + redS[1];
    const float S2 = redS[2] + redS[3];
    float Mtot = 0.f;
#pragma unroll
    for (int w = 0; w < 16; ++w) Mtot += redM[w];
    const float dinv = 1.0f / (S1 * S2 - Mtot);

    // ---- phase 3: rs/cs with per-row masked counts (4 threads per row/col) ----
    {
        const int rr  = tid >> 2;          // 0..255
        const int sub = tid & 3;
        int c2 = 0;
        if (rr < LL) {
            if (rr < l1) {
                const float si = s1[rr];
#pragma unroll 4
                for (int k = 0; k < 32; ++k) {
                    const int j = sub + 4 * k;
                    if (j < l2 && fabsf(si - s2[j]) < 1e-7f) c2++;
                }
            }
        } else {
            const int jj = rr - LL;
            if (jj < l2) {
                const float sj = s2[jj];
#pragma unroll 4
                for (int k = 0; k < 32; ++k) {
                    const int i = sub + 4 * k;
                    if (i < l1 && fabsf(s1[i] - sj) < 1e-7f) c2++;
                }
            }
        }
        c2 += __shfl_xor(c2, 1, 64);
        c2 += __shfl_xor(c2, 2, 64);
        if (sub == 0) {
            if (rr < LL)
                rsv[rr] = (rr < l1) ? (E1[rr] * S2 - (float)c2) * dinv : 0.f;
            else
                csv[rr - LL] = (rr - LL < l2) ? (E2m[rr - LL] * S1 - (float)c2) * dinv : 0.f;
        }
    }
    __syncthreads();

    // ---- phase 4: pooled[d] (a1/a2 re-read from L2), 4 row-groups x 256 d ----
    {
        const int d = tid & 255;
        const int g = tid >> 8;            // 0..3
        float p = 0.f;
#pragma unroll 8
        for (int k = 0; k < 32; ++k) {
            const int i = g * 32 + k;
            p += rsv[i] * A1[i * DD + d] - csv[i] * A2[i * DD + d];
        }
        part[tid] = p;
    }
    __syncthreads();
    if (tid < DD) {
        ((float*)ps4)[tid] = part[tid] + part[256 + tid] + part[512 + tid] + part[768 + tid];
    }
    __syncthreads();

    // ---- phase 5: FC + tanh, 16 threads per h-row, 64 rows/pass, 16 passes ----
    {
        const int hl  = tid >> 4;          // 0..63
        const int t16 = tid & 15;
        // this thread's 4 pooled fragments are invariant across passes
        const float4 u0 = ps4[t16];
        const float4 u1 = ps4[16 + t16];
        const float4 u2 = ps4[32 + t16];
        const float4 u3 = ps4[48 + t16];
        float* __restrict__ outb = out + (size_t)b * HH;
#pragma unroll 4
        for (int pass = 0; pass < 16; ++pass) {
            const int h = pass * 64 + hl;
            const float4* __restrict__ wrow = (const float4*)(fcw + (size_t)h * DD);
            const float4 v0 = wrow[t16];
            const float4 v1 = wrow[16 + t16];
            const float4 v2 = wrow[32 + t16];
            const float4 v3 = wrow[48 + t16];
            float acc = v0.x * u0.x + v0.y * u0.y + v0.z * u0.z + v0.w * u0.w;
            acc      += v1.x * u1.x + v1.y * u1.y + v1.z * u1.z + v1.w * u1.w;
            acc      += v2.x * u2.x + v2.y * u2.y + v2.z * u2.z + v2.w * u2.w;
            acc      += v3.x * u3.x + v3.y * u3.y + v3.z * u3.z + v3.w * u3.w;
            acc += __shfl_xor(acc, 1, 64);
            acc += __shfl_xor(acc, 2, 64);
            acc += __shfl_xor(acc, 4, 64);
            acc += __shfl_xor(acc, 8, 64);
            if (t16 == 0) outb[h] = tanhf(acc + fcb[h]);
        }
    }
}

extern "C" void kernel_launch(void* const* d_in, const int* in_sizes, int n_in,
                              void* d_out, int out_size, void* d_ws, size_t ws_size,
                              hipStream_t stream) {
    const float* a1   = (const float*)d_in[0];
    const int*   len1 = (const int*)d_in[1];
    const float* a2   = (const float*)d_in[2];
    const int*   len2 = (const int*)d_in[3];
    const float* fcw  = (const float*)d_in[4];
    const float* fcb  = (const float*)d_in[5];
    const float* ww   = (const float*)d_in[6];
    float* out = (float*)d_out;

    batch_all_kernel<<<BB, 1024, 0, stream>>>(a1, len1, a2, len2, fcw, fcb, ww, out);
}